// Round 1
// baseline (224.725 us; speedup 1.0000x reference)
//
#include <hip/hip_runtime.h>
#include <hip/hip_bf16.h>
#include <stdint.h>

#define N_NODES  20000
#define N_EDGES  160000
#define F_IN     512
#define HIDDEN   512
#define N_CLS    40
#define M_PAD    20096   // 157 * 128

typedef __bf16 bf16;
typedef __attribute__((ext_vector_type(8))) __bf16 bf16x8;
typedef __attribute__((ext_vector_type(4))) float floatx4;

__device__ inline floatx4 zero4() { floatx4 z = {0.f, 0.f, 0.f, 0.f}; return z; }

// ---------------- conversion / packing ----------------

// one thread per 8 elements of xb [M_PAD x 512]; pad rows -> 0
__global__ void convert_x_kernel(const float* __restrict__ x, bf16* __restrict__ xb) {
    long t  = (long)blockIdx.x * blockDim.x + threadIdx.x;
    long e0 = t * 8;
    if (e0 >= (long)M_PAD * F_IN) return;
    int row = (int)(e0 / F_IN);
    bf16x8 v;
    if (row < N_NODES) {
        const float4* p = (const float4*)(x + e0);
        float4 f0 = p[0], f1 = p[1];
        v[0] = (bf16)f0.x; v[1] = (bf16)f0.y; v[2] = (bf16)f0.z; v[3] = (bf16)f0.w;
        v[4] = (bf16)f1.x; v[5] = (bf16)f1.y; v[6] = (bf16)f1.z; v[7] = (bf16)f1.w;
    } else {
        for (int j = 0; j < 8; ++j) v[j] = (bf16)0.f;
    }
    *(bf16x8*)(xb + e0) = v;
}

// W1T[n][k] = W1[k][n], bf16   (512x512)
__global__ void w1t_kernel(const float* __restrict__ W1, bf16* __restrict__ W1T) {
    int t = blockIdx.x * blockDim.x + threadIdx.x;   // 262144
    int n = t >> 9, k = t & 511;
    W1T[t] = (bf16)W1[(k << 9) + n];
}

// pack W2 (512x40) into MFMA B-fragment order, N padded to 48
// read index in gemm2: ((kt*3+nb)*64 + lane)*8 + j
__global__ void w2pack_kernel(const float* __restrict__ W2, bf16* __restrict__ P) {
    int t = blockIdx.x * blockDim.x + threadIdx.x;   // 24576
    if (t >= 16 * 3 * 64 * 8) return;
    int j = t & 7; int e = t >> 3;
    int lane = e & 63; e >>= 6;
    int nb = e % 3; int kt = e / 3;
    int k = kt * 32 + (lane >> 4) * 8 + j;
    int n = nb * 16 + (lane & 15);
    float v = (n < N_CLS) ? W2[k * N_CLS + n] : 0.f;
    P[t] = (bf16)v;
}

// ---------------- graph prep ----------------

__global__ void degree_kernel(const int* __restrict__ ei, int* __restrict__ deg) {
    int e = blockIdx.x * blockDim.x + threadIdx.x;
    if (e < N_EDGES) atomicAdd(&deg[ei[N_EDGES + e]], 1);
}

__global__ void dis_kernel(const int* __restrict__ deg, float* __restrict__ dis) {
    int i = blockIdx.x * blockDim.x + threadIdx.x;
    if (i < N_NODES) dis[i] = rsqrtf((float)(deg[i] + 1));   // +1 self-loop; always > 0
}

// exclusive scan of deg -> rowptr (single block, 1024 threads)
__global__ void scan_kernel(const int* __restrict__ deg, int* __restrict__ rowptr) {
    __shared__ int sh[1024];
    __shared__ int carry_s;
    int t = threadIdx.x;
    if (t == 0) carry_s = 0;
    __syncthreads();
    for (int base = 0; base < N_NODES; base += 1024) {
        int v = (base + t < N_NODES) ? deg[base + t] : 0;
        sh[t] = v;
        __syncthreads();
        for (int off = 1; off < 1024; off <<= 1) {
            int x = (t >= off) ? sh[t - off] : 0;
            __syncthreads();
            sh[t] += x;
            __syncthreads();
        }
        int carry = carry_s;
        if (base + t < N_NODES) rowptr[base + t] = carry + sh[t] - v;
        __syncthreads();
        if (t == 1023) carry_s = carry + sh[1023];
        __syncthreads();
    }
    if (t == 0) rowptr[N_NODES] = carry_s;
}

__global__ void fill_kernel(const int* __restrict__ ei, const int* __restrict__ rowptr,
                            int* __restrict__ cursor, int* __restrict__ col) {
    int e = blockIdx.x * blockDim.x + threadIdx.x;
    if (e >= N_EDGES) return;
    int d = ei[N_EDGES + e];
    int pos = rowptr[d] + atomicAdd(&cursor[d], 1);
    col[pos] = ei[e];
}

// ---------------- GEMM1: C[M_PAD,512] = A[M_PAD,512] @ W1, bf16 MFMA ----------------
// BT is W1 transposed [n][k]. 128x128 tile, BK=32, 4 waves, each 64x64.
// LDS rows padded to 40 bf16 (80 B): rows 0..7 cover all 32 banks once -> 2-way (free).

__global__ __launch_bounds__(256) void gemm1_kernel(const bf16* __restrict__ A,
                                                    const bf16* __restrict__ BT,
                                                    bf16* __restrict__ C) {
    __shared__ bf16 As[128 * 40];
    __shared__ bf16 Bs[128 * 40];
    const int tid  = threadIdx.x;
    const int lane = tid & 63;
    const int w    = tid >> 6;
    const int wm   = w >> 1, wn = w & 1;
    const int m0   = blockIdx.x * 128;
    const int n0   = blockIdx.y * 128;
    const int fr   = lane & 15, fq = lane >> 4;

    floatx4 acc[4][4];
    for (int mb = 0; mb < 4; ++mb)
        for (int nb = 0; nb < 4; ++nb) acc[mb][nb] = zero4();

    const int r_a = tid >> 2;      // 0..63 (and +64 for second load)
    const int seg = tid & 3;
    const bf16* Ag = A  + (long)(m0 + r_a) * 512 + seg * 8;
    const bf16* Bg = BT + (long)(n0 + r_a) * 512 + seg * 8;
    bf16* Al = As + r_a * 40 + seg * 8;
    bf16* Bl = Bs + r_a * 40 + seg * 8;

    for (int kt = 0; kt < 16; ++kt) {
        const int k0 = kt * 32;
        uint4 a0 = *(const uint4*)(Ag + k0);
        uint4 a1 = *(const uint4*)(Ag + k0 + 64 * 512);
        uint4 b0 = *(const uint4*)(Bg + k0);
        uint4 b1 = *(const uint4*)(Bg + k0 + 64 * 512);
        __syncthreads();
        *(uint4*)Al              = a0;
        *(uint4*)(Al + 64 * 40)  = a1;
        *(uint4*)Bl              = b0;
        *(uint4*)(Bl + 64 * 40)  = b1;
        __syncthreads();
        bf16x8 af[4], bfr[4];
        for (int mb = 0; mb < 4; ++mb)
            af[mb]  = *(const bf16x8*)(As + (wm * 64 + mb * 16 + fr) * 40 + fq * 8);
        for (int nb = 0; nb < 4; ++nb)
            bfr[nb] = *(const bf16x8*)(Bs + (wn * 64 + nb * 16 + fr) * 40 + fq * 8);
        for (int mb = 0; mb < 4; ++mb)
            for (int nb = 0; nb < 4; ++nb)
                acc[mb][nb] = __builtin_amdgcn_mfma_f32_16x16x32_bf16(af[mb], bfr[nb], acc[mb][nb], 0, 0, 0);
    }

    for (int mb = 0; mb < 4; ++mb)
        for (int nb = 0; nb < 4; ++nb) {
            int row0 = m0 + wm * 64 + mb * 16 + fq * 4;
            int col  = n0 + wn * 64 + nb * 16 + fr;
            for (int r = 0; r < 4; ++r)
                C[(long)(row0 + r) * 512 + col] = (bf16)acc[mb][nb][r];
        }
}

// ---------------- aggregation 1: a1 = relu(Anorm @ h1 + b1), bf16 out ----------------
// one wave per node; lane owns 8 contiguous feats (16B loads, 1KB/wave per edge)

__global__ void agg1_kernel(const bf16* __restrict__ H1, const float* __restrict__ dis,
                            const int* __restrict__ rowptr, const int* __restrict__ col,
                            const float* __restrict__ b1, bf16* __restrict__ A1) {
    const int i = blockIdx.x;
    const int l = threadIdx.x;
    bf16* outp = A1 + (long)i * 512 + l * 8;
    if (i >= N_NODES) {            // zero pad rows for GEMM2
        bf16x8 z;
        for (int j = 0; j < 8; ++j) z[j] = (bf16)0.f;
        *(bf16x8*)outp = z;
        return;
    }
    const float di = dis[i];
    float acc[8];
    {
        bf16x8 v = *(const bf16x8*)(H1 + (long)i * 512 + l * 8);
        const float wi = di * di;   // self-loop norm
        for (int j = 0; j < 8; ++j) acc[j] = (float)v[j] * wi;
    }
    const int e1 = rowptr[i + 1];
    for (int e = rowptr[i]; e < e1; ++e) {
        const int s = col[e];
        const float wt = dis[s] * di;
        bf16x8 u = *(const bf16x8*)(H1 + (long)s * 512 + l * 8);
        for (int j = 0; j < 8; ++j) acc[j] += (float)u[j] * wt;
    }
    const float4* bp = (const float4*)(b1 + l * 8);
    float4 c0 = bp[0], c1 = bp[1];
    float bb[8] = {c0.x, c0.y, c0.z, c0.w, c1.x, c1.y, c1.z, c1.w};
    bf16x8 o;
    for (int j = 0; j < 8; ++j) {
        float f = acc[j] + bb[j];
        f = f > 0.f ? f : 0.f;      // relu
        o[j] = (bf16)f;
    }
    *(bf16x8*)outp = o;
}

// ---------------- GEMM2: H2[M_PAD,48] = A1 @ W2 (N padded 40->48) ----------------

__global__ __launch_bounds__(256) void gemm2_kernel(const bf16* __restrict__ A,
                                                    const bf16* __restrict__ P,
                                                    float* __restrict__ H2) {
    const int tid = threadIdx.x, lane = tid & 63, w = tid >> 6;
    const int m0 = blockIdx.x * 64 + w * 16;
    const int fr = lane & 15, fq = lane >> 4;
    const bf16* Ap = A + (long)(m0 + fr) * 512 + fq * 8;
    floatx4 acc[3];
    for (int nb = 0; nb < 3; ++nb) acc[nb] = zero4();
    for (int kt = 0; kt < 16; ++kt) {
        bf16x8 af = *(const bf16x8*)(Ap + kt * 32);
        for (int nb = 0; nb < 3; ++nb) {
            bf16x8 bfr = *(const bf16x8*)(P + ((kt * 3 + nb) * 64 + lane) * 8);
            acc[nb] = __builtin_amdgcn_mfma_f32_16x16x32_bf16(af, bfr, acc[nb], 0, 0, 0);
        }
    }
    for (int nb = 0; nb < 3; ++nb)
        for (int r = 0; r < 4; ++r)
            H2[(long)(m0 + fq * 4 + r) * 48 + nb * 16 + fr] = acc[nb][r];
}

// ---------------- aggregation 2: out = Anorm @ h2 + b2 (f32) ----------------

__global__ void agg2_kernel(const float* __restrict__ H2, const float* __restrict__ dis,
                            const int* __restrict__ rowptr, const int* __restrict__ col,
                            const float* __restrict__ b2, float* __restrict__ out) {
    const int i = blockIdx.x;
    const int l = threadIdx.x;
    if (l >= N_CLS) return;
    const float di = dis[i];
    float acc = H2[(long)i * 48 + l] * di * di;
    const int e1 = rowptr[i + 1];
    for (int e = rowptr[i]; e < e1; ++e) {
        const int s = col[e];
        acc += H2[(long)s * 48 + l] * (dis[s] * di);
    }
    out[(long)i * N_CLS + l] = acc + b2[l];
}

// ---------------- launch ----------------

extern "C" void kernel_launch(void* const* d_in, const int* in_sizes, int n_in,
                              void* d_out, int out_size, void* d_ws, size_t ws_size,
                              hipStream_t stream) {
    const float* x  = (const float*)d_in[0];
    const int*   ei = (const int*)d_in[1];     // [2 x 160000] int32
    const float* W1 = (const float*)d_in[2];
    const float* b1 = (const float*)d_in[3];
    const float* W2 = (const float*)d_in[4];
    const float* b2 = (const float*)d_in[5];
    float* out = (float*)d_out;

    char* base = (char*)d_ws;
    size_t o = 0;
    auto alloc = [&](size_t bytes) { size_t r = o; o = (o + bytes + 255) & ~(size_t)255; return r; };
    bf16*  xb   = (bf16*)(base + alloc((size_t)M_PAD * 512 * 2));
    bf16*  w1t  = (bf16*)(base + alloc((size_t)512 * 512 * 2));
    bf16*  w2p  = (bf16*)(base + alloc((size_t)24576 * 2));
    bf16*  h1   = (bf16*)(base + alloc((size_t)M_PAD * 512 * 2));
    bf16*  a1   = (bf16*)(base + alloc((size_t)M_PAD * 512 * 2));
    float* h2   = (float*)(base + alloc((size_t)M_PAD * 48 * 4));
    size_t deg_off = alloc((size_t)N_NODES * 4);
    int*   deg  = (int*)(base + deg_off);
    int*   cur  = (int*)(base + alloc((size_t)N_NODES * 4));
    int*   rowp = (int*)(base + alloc((size_t)(N_NODES + 1) * 4));
    int*   col  = (int*)(base + alloc((size_t)N_EDGES * 4));
    float* dis  = (float*)(base + alloc((size_t)N_NODES * 4));

    // zero deg + cursor (adjacent region)
    hipMemsetAsync(base + deg_off, 0, ((char*)rowp - (char*)deg), stream);

    convert_x_kernel<<<(M_PAD * 512 / 8 + 255) / 256, 256, 0, stream>>>(x, xb);
    w1t_kernel<<<262144 / 256, 256, 0, stream>>>(W1, w1t);
    w2pack_kernel<<<(24576 + 255) / 256, 256, 0, stream>>>(W2, w2p);

    degree_kernel<<<(N_EDGES + 255) / 256, 256, 0, stream>>>(ei, deg);
    dis_kernel<<<(N_NODES + 255) / 256, 256, 0, stream>>>(deg, dis);
    scan_kernel<<<1, 1024, 0, stream>>>(deg, rowp);
    fill_kernel<<<(N_EDGES + 255) / 256, 256, 0, stream>>>(ei, rowp, cur, col);

    gemm1_kernel<<<dim3(M_PAD / 128, 512 / 128), 256, 0, stream>>>(xb, w1t, h1);
    agg1_kernel<<<M_PAD, 64, 0, stream>>>(h1, dis, rowp, col, b1, a1);
    gemm2_kernel<<<M_PAD / 64, 256, 0, stream>>>(a1, w2p, h2);
    agg2_kernel<<<N_NODES, 64, 0, stream>>>(h2, dis, rowp, col, b2, out);
}

// Round 2
// 207.505 us; speedup vs baseline: 1.0830x; 1.0830x over previous
//
#include <hip/hip_runtime.h>
#include <hip/hip_bf16.h>
#include <stdint.h>

#define N_NODES  20000
#define N_EDGES  160000
#define F_IN     512
#define HIDDEN   512
#define N_CLS    40
#define M_PAD    20096   // 157 * 128
#define DEG_PAD  20480   // 1024 * 20, for the scan kernel's int4 loads

typedef __bf16 bf16;
typedef __attribute__((ext_vector_type(8))) __bf16 bf16x8;
typedef __attribute__((ext_vector_type(4))) float floatx4;

__device__ inline floatx4 zero4() { floatx4 z = {0.f, 0.f, 0.f, 0.f}; return z; }

// async global->LDS, 16B per lane; LDS dest = wave-uniform base + lane*16
typedef __attribute__((address_space(3))) uint32_t lds_u32;
typedef __attribute__((address_space(1))) const uint32_t glb_u32;
__device__ inline void ldst16(const bf16* g, bf16* l) {
    __builtin_amdgcn_global_load_lds((glb_u32*)g, (lds_u32*)l, 16, 0, 0);
}

// ---------------- fused prep: convert_x | W1^T | W2 pack | degree ----------------
// block ranges: [0,5024) convert, [5024,5152) w1t, [5152,5248) w2pack, [5248,5873) degree

#define NB_CONV 5024
#define NB_W1T  128
#define NB_W2P  96
#define NB_DEG  625
#define NB_PREP (NB_CONV + NB_W1T + NB_W2P + NB_DEG)

__global__ void prep_kernel(const float* __restrict__ x, bf16* __restrict__ xb,
                            const float* __restrict__ W1, bf16* __restrict__ W1T,
                            const float* __restrict__ W2, bf16* __restrict__ W2P,
                            const int* __restrict__ ei, int* __restrict__ deg) {
    const int b = blockIdx.x, tid = threadIdx.x;
    if (b < NB_CONV) {
        // xb[M_PAD x 512] bf16, pad rows -> 0; 8 elems/thread
        long e0 = ((long)b * 256 + tid) * 8;
        int row = (int)(e0 >> 9);
        bf16x8 v;
        if (row < N_NODES) {
            const float4* p = (const float4*)(x + e0);
            float4 f0 = p[0], f1 = p[1];
            v[0] = (bf16)f0.x; v[1] = (bf16)f0.y; v[2] = (bf16)f0.z; v[3] = (bf16)f0.w;
            v[4] = (bf16)f1.x; v[5] = (bf16)f1.y; v[6] = (bf16)f1.z; v[7] = (bf16)f1.w;
        } else {
            for (int j = 0; j < 8; ++j) v[j] = (bf16)0.f;
        }
        *(bf16x8*)(xb + e0) = v;
    } else if (b < NB_CONV + NB_W1T) {
        // W1T[n][k0..k0+8) = W1[k][n]; lane-consecutive n -> coalesced reads
        int t  = (b - NB_CONV) * 256 + tid;    // < 32768
        int n  = t & 511;
        int k0 = (t >> 9) * 8;
        bf16x8 v;
        for (int j = 0; j < 8; ++j) v[j] = (bf16)W1[((k0 + j) << 9) + n];
        *(bf16x8*)(W1T + n * 512 + k0) = v;
    } else if (b < NB_CONV + NB_W1T + NB_W2P) {
        // pack W2 (512x40) into gemm2 B-fragment order, N padded to 48
        int t = (b - NB_CONV - NB_W1T) * 256 + tid;   // < 24576
        int j = t & 7; int e = t >> 3;
        int lane = e & 63; e >>= 6;
        int nb = e % 3; int kt = e / 3;
        int k = kt * 32 + (lane >> 4) * 8 + j;
        int n = nb * 16 + (lane & 15);
        float v = (n < N_CLS) ? W2[k * N_CLS + n] : 0.f;
        W2P[t] = (bf16)v;
    } else {
        int e = (b - NB_CONV - NB_W1T - NB_W2P) * 256 + tid;
        if (e < N_EDGES) atomicAdd(&deg[ei[N_EDGES + e]], 1);
    }
}

// ---------------- scan + dis + cursor init (single block, 20 elems/thread) ----------------

__global__ __launch_bounds__(1024) void scan_dis_kernel(const int* __restrict__ deg,
                                                        int* __restrict__ rowptr,
                                                        int* __restrict__ cur,
                                                        float* __restrict__ dis) {
    __shared__ int sh[1024];
    const int t = threadIdx.x;
    const int base = t * 20;
    int vals[20];
    {   // 5 x int4 coalesced loads (deg padded to DEG_PAD, zeros beyond N_NODES)
        const int4* dp = (const int4*)(deg + base);
        for (int q = 0; q < 5; ++q) {
            int4 v = dp[q];
            vals[q * 4 + 0] = v.x; vals[q * 4 + 1] = v.y;
            vals[q * 4 + 2] = v.z; vals[q * 4 + 3] = v.w;
        }
    }
    int loc[20];
    int sum = 0;
    for (int j = 0; j < 20; ++j) { loc[j] = sum; sum += vals[j]; }
    sh[t] = sum;
    __syncthreads();
    for (int off = 1; off < 1024; off <<= 1) {
        int xv = (t >= off) ? sh[t - off] : 0;
        __syncthreads();
        sh[t] += xv;
        __syncthreads();
    }
    const int incl = sh[t];
    const int excl = incl - sum;
    for (int j = 0; j < 20; ++j) {
        int idx = base + j;
        if (idx < N_NODES) {
            int r = excl + loc[j];
            rowptr[idx] = r;
            cur[idx]    = r;                       // fill uses cur directly
            dis[idx]    = rsqrtf((float)(vals[j] + 1));   // +1 self-loop
        }
    }
    if (t == 1023) rowptr[N_NODES] = incl;
}

__global__ void fill_kernel(const int* __restrict__ ei, int* __restrict__ cur,
                            int* __restrict__ col) {
    int e = blockIdx.x * blockDim.x + threadIdx.x;
    if (e >= N_EDGES) return;
    int d = ei[N_EDGES + e];
    int pos = atomicAdd(&cur[d], 1);
    col[pos] = ei[e];
}

// ---------------- GEMM1: C[M_PAD,512] = A @ W1 (BT = W1^T), m97 structure ----------------
// 128x128 tile, BK=32, 4 waves. LDS [128][32] bf16 unpadded (global_load_lds constraint:
// dest = wave-uniform base + lane*16). Wave w stages rows w*32..w*32+31 via 2 insts/buffer.

__global__ __launch_bounds__(256) void gemm1_kernel(const bf16* __restrict__ A,
                                                    const bf16* __restrict__ BT,
                                                    bf16* __restrict__ C) {
    __shared__ bf16 As[128 * 32];
    __shared__ bf16 Bs[128 * 32];
    const int tid  = threadIdx.x;
    const int lane = tid & 63;
    const int w    = tid >> 6;
    const int wm   = w >> 1, wn = w & 1;
    const int m0   = blockIdx.x * 128;
    const int n0   = blockIdx.y * 128;
    const int fr   = lane & 15, fq = lane >> 4;

    floatx4 acc[4][4];
    for (int mb = 0; mb < 4; ++mb)
        for (int nb = 0; nb < 4; ++nb) acc[mb][nb] = zero4();

    const int sr = lane >> 2;          // staging row within 16-row group
    const int sk = (lane & 3) * 8;     // k-elem offset (16B granule)
    const bf16* Ag = A  + (long)(m0 + w * 32 + sr) * 512 + sk;
    const bf16* Bg = BT + (long)(n0 + w * 32 + sr) * 512 + sk;
    bf16* Asw = As + w * 1024;         // wave-uniform LDS base (elems)
    bf16* Bsw = Bs + w * 1024;

    for (int kt = 0; kt < 16; ++kt) {
        const int k0 = kt * 32;
        __syncthreads();                       // prev compute done before overwrite
        ldst16(Ag + k0,            Asw);       // rows w*32 .. +15
        ldst16(Ag + k0 + 16 * 512, Asw + 512); // rows w*32+16 .. +31
        ldst16(Bg + k0,            Bsw);
        ldst16(Bg + k0 + 16 * 512, Bsw + 512);
        __syncthreads();                       // compiler drains vmcnt before barrier
        bf16x8 af[4], bfv[4];
        for (int mb = 0; mb < 4; ++mb)
            af[mb]  = *(const bf16x8*)(As + (wm * 64 + mb * 16 + fr) * 32 + fq * 8);
        for (int nb = 0; nb < 4; ++nb)
            bfv[nb] = *(const bf16x8*)(Bs + (wn * 64 + nb * 16 + fr) * 32 + fq * 8);
        for (int mb = 0; mb < 4; ++mb)
            for (int nb = 0; nb < 4; ++nb)
                acc[mb][nb] = __builtin_amdgcn_mfma_f32_16x16x32_bf16(af[mb], bfv[nb], acc[mb][nb], 0, 0, 0);
    }

    for (int mb = 0; mb < 4; ++mb)
        for (int nb = 0; nb < 4; ++nb) {
            int row0 = m0 + wm * 64 + mb * 16 + fq * 4;
            int col  = n0 + wn * 64 + nb * 16 + fr;
            for (int r = 0; r < 4; ++r)
                C[(long)(row0 + r) * 512 + col] = (bf16)acc[mb][nb][r];
        }
}

// ---------------- aggregation 1: a1 = relu(Anorm @ h1 + b1), bf16 ----------------

__global__ void agg1_kernel(const bf16* __restrict__ H1, const float* __restrict__ dis,
                            const int* __restrict__ rowptr, const int* __restrict__ col,
                            const float* __restrict__ b1, bf16* __restrict__ A1) {
    const int i = blockIdx.x;
    const int l = threadIdx.x;
    bf16* outp = A1 + (long)i * 512 + l * 8;
    if (i >= N_NODES) {            // zero pad rows for GEMM2
        bf16x8 z;
        for (int j = 0; j < 8; ++j) z[j] = (bf16)0.f;
        *(bf16x8*)outp = z;
        return;
    }
    const float di = dis[i];
    float acc[8];
    {
        bf16x8 v = *(const bf16x8*)(H1 + (long)i * 512 + l * 8);
        const float wi = di * di;
        for (int j = 0; j < 8; ++j) acc[j] = (float)v[j] * wi;
    }
    const int e1 = rowptr[i + 1];
    for (int e = rowptr[i]; e < e1; ++e) {
        const int s = col[e];
        const float wt = dis[s] * di;
        bf16x8 u = *(const bf16x8*)(H1 + (long)s * 512 + l * 8);
        for (int j = 0; j < 8; ++j) acc[j] += (float)u[j] * wt;
    }
    const float4* bp = (const float4*)(b1 + l * 8);
    float4 c0 = bp[0], c1 = bp[1];
    float bb[8] = {c0.x, c0.y, c0.z, c0.w, c1.x, c1.y, c1.z, c1.w};
    bf16x8 o;
    for (int j = 0; j < 8; ++j) {
        float f = acc[j] + bb[j];
        f = f > 0.f ? f : 0.f;
        o[j] = (bf16)f;
    }
    *(bf16x8*)outp = o;
}

// ---------------- GEMM2: H2[M_PAD,48] = A1 @ W2 (N padded 40->48) ----------------

__global__ __launch_bounds__(256) void gemm2_kernel(const bf16* __restrict__ A,
                                                    const bf16* __restrict__ P,
                                                    float* __restrict__ H2) {
    const int tid = threadIdx.x, lane = tid & 63, w = tid >> 6;
    const int m0 = blockIdx.x * 64 + w * 16;
    const int fr = lane & 15, fq = lane >> 4;
    const bf16* Ap = A + (long)(m0 + fr) * 512 + fq * 8;
    floatx4 acc[3];
    for (int nb = 0; nb < 3; ++nb) acc[nb] = zero4();
    for (int kt = 0; kt < 16; ++kt) {
        bf16x8 af = *(const bf16x8*)(Ap + kt * 32);
        for (int nb = 0; nb < 3; ++nb) {
            bf16x8 bfr = *(const bf16x8*)(P + ((kt * 3 + nb) * 64 + lane) * 8);
            acc[nb] = __builtin_amdgcn_mfma_f32_16x16x32_bf16(af, bfr, acc[nb], 0, 0, 0);
        }
    }
    for (int nb = 0; nb < 3; ++nb)
        for (int r = 0; r < 4; ++r)
            H2[(long)(m0 + fq * 4 + r) * 48 + nb * 16 + fr] = acc[nb][r];
}

// ---------------- aggregation 2: out = Anorm @ h2 + b2 (f32) ----------------

__global__ void agg2_kernel(const float* __restrict__ H2, const float* __restrict__ dis,
                            const int* __restrict__ rowptr, const int* __restrict__ col,
                            const float* __restrict__ b2, float* __restrict__ out) {
    const int i = blockIdx.x;
    const int l = threadIdx.x;
    if (l >= N_CLS) return;
    const float di = dis[i];
    float acc = H2[(long)i * 48 + l] * di * di;
    const int e1 = rowptr[i + 1];
    for (int e = rowptr[i]; e < e1; ++e) {
        const int s = col[e];
        acc += H2[(long)s * 48 + l] * (dis[s] * di);
    }
    out[(long)i * N_CLS + l] = acc + b2[l];
}

// ---------------- launch ----------------

extern "C" void kernel_launch(void* const* d_in, const int* in_sizes, int n_in,
                              void* d_out, int out_size, void* d_ws, size_t ws_size,
                              hipStream_t stream) {
    const float* x  = (const float*)d_in[0];
    const int*   ei = (const int*)d_in[1];     // [2 x 160000] int32
    const float* W1 = (const float*)d_in[2];
    const float* b1 = (const float*)d_in[3];
    const float* W2 = (const float*)d_in[4];
    const float* b2 = (const float*)d_in[5];
    float* out = (float*)d_out;

    char* base = (char*)d_ws;
    size_t o = 0;
    auto alloc = [&](size_t bytes) { size_t r = o; o = (o + bytes + 255) & ~(size_t)255; return r; };
    bf16*  xb   = (bf16*)(base + alloc((size_t)M_PAD * 512 * 2));
    bf16*  w1t  = (bf16*)(base + alloc((size_t)512 * 512 * 2));
    bf16*  w2p  = (bf16*)(base + alloc((size_t)24576 * 2));
    bf16*  h1   = (bf16*)(base + alloc((size_t)M_PAD * 512 * 2));
    bf16*  a1   = (bf16*)(base + alloc((size_t)M_PAD * 512 * 2));
    float* h2   = (float*)(base + alloc((size_t)M_PAD * 48 * 4));
    size_t deg_off = alloc((size_t)DEG_PAD * 4);
    int*   deg  = (int*)(base + deg_off);
    int*   cur  = (int*)(base + alloc((size_t)N_NODES * 4));
    int*   rowp = (int*)(base + alloc((size_t)(N_NODES + 1) * 4));
    int*   col  = (int*)(base + alloc((size_t)N_EDGES * 4));
    float* dis  = (float*)(base + alloc((size_t)N_NODES * 4));

    hipMemsetAsync(deg, 0, (size_t)DEG_PAD * 4, stream);   // only deg needs zeroing

    prep_kernel<<<NB_PREP, 256, 0, stream>>>(x, xb, W1, w1t, W2, w2p, ei, deg);
    scan_dis_kernel<<<1, 1024, 0, stream>>>(deg, rowp, cur, dis);
    fill_kernel<<<(N_EDGES + 255) / 256, 256, 0, stream>>>(ei, cur, col);

    gemm1_kernel<<<dim3(M_PAD / 128, 512 / 128), 256, 0, stream>>>(xb, w1t, h1);
    agg1_kernel<<<M_PAD, 64, 0, stream>>>(h1, dis, rowp, col, b1, a1);
    gemm2_kernel<<<M_PAD / 64, 256, 0, stream>>>(a1, w2p, h2);
    agg2_kernel<<<N_NODES, 64, 0, stream>>>(h2, dis, rowp, col, b2, out);
}